// Round 24
// baseline (43.328 us; speedup 1.0000x reference)
//
#include <hip/hip_runtime.h>
#include <hip/hip_fp16.h>

#define B_   8
#define LQ_  128
#define LK_  1024
#define H_   128

// tanh(q+k) = 1 - 2/(EQ*EK + 1), EQ=exp(2q') f32, EK=exp(2k') f16.
// g_ekT4[b][h4][sp] (uint4): uint j = half2( EK[4*h4+j][2*sp], EK[4*h4+j][2*sp+1] )
// g_vh[b][s][v2] half2 along v. Measured absmax 1.95e-3 (R13-R23), thr 8.3e-3.
__device__ float        g_eq  [B_ * LQ_ * H_];
__device__ uint4        g_ekT4[B_ * (H_ / 4) * (LK_ / 2)];
__device__ unsigned int g_vh  [B_ * LK_ * (H_ / 2)];

#define C2LOG2E 2.8853900817779268f      // 2/ln2

// Merged projection + values-pack. (R17-proven, unchanged)
__global__ __launch_bounds__(256) void proj_conv(const float* __restrict__ q,
                                                 const float* __restrict__ k,
                                                 const float* __restrict__ Wq,
                                                 const float* __restrict__ Wk,
                                                 const float* __restrict__ values) {
    const int bx = blockIdx.x, ch = blockIdx.y;
    const int t = threadIdx.x;
    if (bx >= 288) {                     // ---- values pack ----
        const int idx = ((bx - 288) + (ch << 9)) * 256 + t;
        float4 v = *(const float4*)(values + (size_t)idx * 4);
        __half2 p0 = __floats2half2_rn(v.x, v.y);
        __half2 p1 = __floats2half2_rn(v.z, v.w);
        *(uint2*)(g_vh + (size_t)idx * 2) =
            make_uint2(*(unsigned int*)&p0, *(unsigned int*)&p1);
        return;
    }
    __shared__ float Ws[H_ * 64];
    __shared__ float Xs[32 * H_];
    const bool isq = (bx < 32);
    const float* X; const float* W; int r0;
    if (isq) { X = q; W = Wq; r0 = bx * 32; }
    else     { X = k; W = Wk; r0 = (bx - 32) * 32; }

    #pragma unroll
    for (int u = 0; u < 8; ++u) {
        int p = u * 256 + t;
        int kk = p >> 4, c4 = p & 15;
        *(float4*)(Ws + kk * 64 + c4 * 4) = *(const float4*)(W + kk * H_ + ch * 64 + c4 * 4);
    }
    #pragma unroll
    for (int u = 0; u < 4; ++u) {
        int idx = u * 256 + t;
        int r = idx >> 5, c = idx & 31;
        *(float4*)(Xs + r * H_ + c * 4) = *(const float4*)(X + (size_t)(r0 + r) * H_ + c * 4);
    }
    __syncthreads();

    const int rr = t >> 4;               // [0,16): 2 rows
    const int cc = t & 15;               // [0,16): 4 cols
    float acc[2][4] = {};
    #pragma unroll 4
    for (int kk = 0; kk < H_; ++kk) {
        float4 w4 = *(const float4*)(Ws + kk * 64 + cc * 4);
        float x0 = Xs[(rr * 2) * H_ + kk];
        float x1 = Xs[(rr * 2 + 1) * H_ + kk];
        acc[0][0] = fmaf(x0, w4.x, acc[0][0]); acc[0][1] = fmaf(x0, w4.y, acc[0][1]);
        acc[0][2] = fmaf(x0, w4.z, acc[0][2]); acc[0][3] = fmaf(x0, w4.w, acc[0][3]);
        acc[1][0] = fmaf(x1, w4.x, acc[1][0]); acc[1][1] = fmaf(x1, w4.y, acc[1][1]);
        acc[1][2] = fmaf(x1, w4.z, acc[1][2]); acc[1][3] = fmaf(x1, w4.w, acc[1][3]);
    }
    if (isq) {
        #pragma unroll
        for (int i = 0; i < 2; ++i) {
            float4 o;
            o.x = __builtin_amdgcn_exp2f(acc[i][0] * C2LOG2E);
            o.y = __builtin_amdgcn_exp2f(acc[i][1] * C2LOG2E);
            o.z = __builtin_amdgcn_exp2f(acc[i][2] * C2LOG2E);
            o.w = __builtin_amdgcn_exp2f(acc[i][3] * C2LOG2E);
            *(float4*)(g_eq + (size_t)(r0 + rr * 2 + i) * H_ + ch * 64 + cc * 4) = o;
        }
    } else {
        const int b  = r0 >> 10;
        const int s0 = (r0 & 1023) + rr * 2;
        const int h4 = ch * 16 + cc;
        uint4 pk;
        #pragma unroll
        for (int j = 0; j < 4; ++j) {
            float e0 = __builtin_amdgcn_exp2f(acc[0][j] * C2LOG2E);
            float e1 = __builtin_amdgcn_exp2f(acc[1][j] * C2LOG2E);
            __half2 p = __floats2half2_rn(e0, e1);
            ((unsigned int*)&pk)[j] = *(unsigned int*)&p;
        }
        g_ekT4[((size_t)b * (H_ / 4) + h4) * (LK_ / 2) + (s0 >> 1)] = pk;
    }
}

// Fused scores + softmax + PV, 2 rows/block, UNIFORM WORK (R24).
// R21-R23 evidence: all-resident grid (no backfill) + work ~ valid_b made
// duration = max-CU work ~ 1.8x mean; every micro-fix nulled because the
// critical path was the unluckiest CU. Fix: every block does IDENTICAL work
// -- compute all 1024 s unconditionally (EK exists for all s), apply the
// mask at the weight store (w = s<valid ? e : 0; zeros are exact no-ops in
// sum and PV -> output bit-identical). valid==0 folds in as w=1 (sum=1024).
// No divergent branches remain; PV bound is compile-time LK_.
__global__ __launch_bounds__(512, 4) void fused_attn(const int* __restrict__ valid_lens,
                                                     const float* __restrict__ w_v,
                                                     float* __restrict__ out) {
    __shared__ float scA[LK_], scB[LK_];
    __shared__ float sredA[8], sredB[8];
    __shared__ float rinvs[2];
    __shared__ float part[16][2][H_];    // 16 KB
    const int t = threadIdx.x;
    const int lane = t & 63, wid = t >> 6;
    const int b = blockIdx.x >> 6, l0 = (blockIdx.x & 63) * 2;
    int valid = valid_lens[b];
    valid = min(max(valid, 0), LK_);

    // ---- Phase 1: unconditional scores; mask folded into the weight store ----
    const int s0 = 2 * t;
    const float* __restrict__ q0 = g_eq + (size_t)(b * LQ_ + l0) * H_;
    const float* __restrict__ q1 = q0 + H_;
    const uint4* __restrict__ ek = g_ekT4 + (size_t)b * (H_ / 4) * (LK_ / 2) + t;
    float a00 = 0.0f, a01 = 0.0f, a10 = 0.0f, a11 = 0.0f;
    #pragma unroll 4
    for (int h4 = 0; h4 < H_ / 4; ++h4) {
        uint4 u = ek[(size_t)h4 * (LK_ / 2)];
        #pragma unroll
        for (int j = 0; j < 4; ++j) {
            unsigned int uj = ((const unsigned int*)&u)[j];
            float2 ef = __half22float2(*(const __half2*)&uj);
            const int h = h4 * 4 + j;
            const float qa = q0[h], qb = q1[h], wh = w_v[h];
            a00 = fmaf(wh, __builtin_amdgcn_rcpf(fmaf(qa, ef.x, 1.0f)), a00);
            a01 = fmaf(wh, __builtin_amdgcn_rcpf(fmaf(qa, ef.y, 1.0f)), a01);
            a10 = fmaf(wh, __builtin_amdgcn_rcpf(fmaf(qb, ef.x, 1.0f)), a10);
            a11 = fmaf(wh, __builtin_amdgcn_rcpf(fmaf(qb, ef.y, 1.0f)), a11);
        }
    }
    const float cexp = -2.0f * 1.44269504f;
    float e00 = __builtin_amdgcn_exp2f(a00 * cexp);
    float e01 = __builtin_amdgcn_exp2f(a01 * cexp);
    float e10 = __builtin_amdgcn_exp2f(a10 * cexp);
    float e11 = __builtin_amdgcn_exp2f(a11 * cexp);
    const bool uni = (valid == 0);       // ref: all -1e6 -> uniform weights
    const bool ok0 = s0 < valid, ok1 = s0 + 1 < valid;
    float w00 = uni ? 1.0f : (ok0 ? e00 : 0.0f);
    float w01 = uni ? 1.0f : (ok1 ? e01 : 0.0f);
    float w10 = uni ? 1.0f : (ok0 ? e10 : 0.0f);
    float w11 = uni ? 1.0f : (ok1 ? e11 : 0.0f);
    *(float2*)(scA + s0) = make_float2(w00, w01);
    *(float2*)(scB + s0) = make_float2(w10, w11);
    float p0 = w00 + w01, p1 = w10 + w11;

    // ---- Phase 2: dual sum reduce (valid==0 gives sum=1024 exactly) ----
    #pragma unroll
    for (int kk = 32; kk; kk >>= 1) {
        p0 += __shfl_xor(p0, kk, 64);
        p1 += __shfl_xor(p1, kk, 64);
    }
    if (lane == 0) { sredA[wid] = p0; sredB[wid] = p1; }
    __syncthreads();
    if (t < 2) {
        const float* sr = t ? sredB : sredA;
        float s8 = ((sr[0] + sr[1]) + (sr[2] + sr[3]))
                 + ((sr[4] + sr[5]) + (sr[6] + sr[7]));
        rinvs[t] = 1.0f / s8;
    }
    __syncthreads();

    // ---- Phase 3: PV over the FULL compile-time range (zeros are no-ops) ----
    const int c = t >> 5;                // s-chunk [0,16)
    const int v4 = t & 31;               // 4-v group
    const uint2* vb = (const uint2*)g_vh + (size_t)b * LK_ * (H_ / 4) + v4;
    float ax0 = 0.0f, ay0 = 0.0f, az0 = 0.0f, aw0 = 0.0f;
    float ax1 = 0.0f, ay1 = 0.0f, az1 = 0.0f, aw1 = 0.0f;
    #pragma unroll 4
    for (int s = c; s < LK_; s += 16) {
        uint2 u = vb[(size_t)s * (H_ / 4)];
        float2 v01 = __half22float2(*(const __half2*)&u.x);
        float2 v23 = __half22float2(*(const __half2*)&u.y);
        float w0 = scA[s], w1 = scB[s];
        ax0 = fmaf(w0, v01.x, ax0); ay0 = fmaf(w0, v01.y, ay0);
        az0 = fmaf(w0, v23.x, az0); aw0 = fmaf(w0, v23.y, aw0);
        ax1 = fmaf(w1, v01.x, ax1); ay1 = fmaf(w1, v01.y, ay1);
        az1 = fmaf(w1, v23.x, az1); aw1 = fmaf(w1, v23.y, aw1);
    }
    *(float4*)(&part[c][0][4 * v4]) = make_float4(ax0, ay0, az0, aw0);
    *(float4*)(&part[c][1][4 * v4]) = make_float4(ax1, ay1, az1, aw1);
    __syncthreads();
    if (t < 256) {
        const int rr = t >> 7, v = t & 127;
        float o = 0.0f;
        #pragma unroll
        for (int cc2 = 0; cc2 < 16; ++cc2) o += part[cc2][rr][v];
        out[(size_t)(b * LQ_ + l0 + rr) * H_ + v] = o * rinvs[rr];
    }
}

extern "C" void kernel_launch(void* const* d_in, const int* in_sizes, int n_in,
                              void* d_out, int out_size, void* d_ws, size_t ws_size,
                              hipStream_t stream) {
    const float* queries    = (const float*)d_in[0];
    const float* keys       = (const float*)d_in[1];
    const float* values     = (const float*)d_in[2];
    const int*   valid_lens = (const int*)d_in[3];
    const float* W_q        = (const float*)d_in[4];
    const float* W_k        = (const float*)d_in[5];
    const float* w_v        = (const float*)d_in[6];
    float* out = (float*)d_out;
    (void)d_ws; (void)ws_size; (void)in_sizes; (void)n_in; (void)out_size;

    proj_conv <<<dim3(800, 2), 256, 0, stream>>>(queries, keys, W_q, W_k, values);
    fused_attn<<<512, 512, 0, stream>>>(valid_lens, w_v, out);
}

// Round 25
// 33.997 us; speedup vs baseline: 1.2745x; 1.2745x over previous
//
#include <hip/hip_runtime.h>
#include <hip/hip_fp16.h>

#define B_   8
#define LQ_  128
#define LK_  1024
#define H_   128

// tanh(q+k) = 1 - 2/(EQ*EK + 1), EQ=exp(2q') f32, EK=exp(2k') f16.
// g_ekT4[b][h4][sp] (uint4): uint j = half2( EK[4*h4+j][2*sp], EK[4*h4+j][2*sp+1] )
//   -> fused phase-1 load = 16B/lane, 4 h x 2 s per load, coalesced 1KB/wave.
// g_vh[b][s][v2] half2 along v (read as uint2 = 4 v). f16 rel err 2^-11;
// measured absmax 1.95e-3 (R13-R24), threshold 8.3e-3.
// This is the R19 kernel, re-submitted verbatim: best measured configuration
// (33.86 us). R18-R24 tested softmax-pass removal, load depth, L2 bytes,
// XCD locality, spill, block retirement, and work uniformity -- all null or
// negative. Session optimum; leaving it in place.
__device__ float        g_eq  [B_ * LQ_ * H_];
__device__ uint4        g_ekT4[B_ * (H_ / 4) * (LK_ / 2)];
__device__ unsigned int g_vh  [B_ * LK_ * (H_ / 2)];

#define C2LOG2E 2.8853900817779268f      // 2/ln2

// Merged projection + values-pack. (R17-proven, unchanged)
__global__ __launch_bounds__(256) void proj_conv(const float* __restrict__ q,
                                                 const float* __restrict__ k,
                                                 const float* __restrict__ Wq,
                                                 const float* __restrict__ Wk,
                                                 const float* __restrict__ values) {
    const int bx = blockIdx.x, ch = blockIdx.y;
    const int t = threadIdx.x;
    if (bx >= 288) {                     // ---- values pack ----
        const int idx = ((bx - 288) + (ch << 9)) * 256 + t;   // [0, 262144)
        float4 v = *(const float4*)(values + (size_t)idx * 4);
        __half2 p0 = __floats2half2_rn(v.x, v.y);
        __half2 p1 = __floats2half2_rn(v.z, v.w);
        *(uint2*)(g_vh + (size_t)idx * 2) =
            make_uint2(*(unsigned int*)&p0, *(unsigned int*)&p1);
        return;
    }
    __shared__ float Ws[H_ * 64];
    __shared__ float Xs[32 * H_];
    const bool isq = (bx < 32);
    const float* X; const float* W; int r0;
    if (isq) { X = q; W = Wq; r0 = bx * 32; }
    else     { X = k; W = Wk; r0 = (bx - 32) * 32; }

    #pragma unroll
    for (int u = 0; u < 8; ++u) {
        int p = u * 256 + t;
        int kk = p >> 4, c4 = p & 15;
        *(float4*)(Ws + kk * 64 + c4 * 4) = *(const float4*)(W + kk * H_ + ch * 64 + c4 * 4);
    }
    #pragma unroll
    for (int u = 0; u < 4; ++u) {
        int idx = u * 256 + t;
        int r = idx >> 5, c = idx & 31;
        *(float4*)(Xs + r * H_ + c * 4) = *(const float4*)(X + (size_t)(r0 + r) * H_ + c * 4);
    }
    __syncthreads();

    const int rr = t >> 4;               // [0,16): 2 rows
    const int cc = t & 15;               // [0,16): 4 cols
    float acc[2][4] = {};
    #pragma unroll 4
    for (int kk = 0; kk < H_; ++kk) {
        float4 w4 = *(const float4*)(Ws + kk * 64 + cc * 4);
        float x0 = Xs[(rr * 2) * H_ + kk];
        float x1 = Xs[(rr * 2 + 1) * H_ + kk];
        acc[0][0] = fmaf(x0, w4.x, acc[0][0]); acc[0][1] = fmaf(x0, w4.y, acc[0][1]);
        acc[0][2] = fmaf(x0, w4.z, acc[0][2]); acc[0][3] = fmaf(x0, w4.w, acc[0][3]);
        acc[1][0] = fmaf(x1, w4.x, acc[1][0]); acc[1][1] = fmaf(x1, w4.y, acc[1][1]);
        acc[1][2] = fmaf(x1, w4.z, acc[1][2]); acc[1][3] = fmaf(x1, w4.w, acc[1][3]);
    }
    if (isq) {
        #pragma unroll
        for (int i = 0; i < 2; ++i) {
            float4 o;
            o.x = __builtin_amdgcn_exp2f(acc[i][0] * C2LOG2E);
            o.y = __builtin_amdgcn_exp2f(acc[i][1] * C2LOG2E);
            o.z = __builtin_amdgcn_exp2f(acc[i][2] * C2LOG2E);
            o.w = __builtin_amdgcn_exp2f(acc[i][3] * C2LOG2E);
            *(float4*)(g_eq + (size_t)(r0 + rr * 2 + i) * H_ + ch * 64 + cc * 4) = o;
        }
    } else {
        const int b  = r0 >> 10;
        const int s0 = (r0 & 1023) + rr * 2;
        const int h4 = ch * 16 + cc;
        uint4 pk;
        #pragma unroll
        for (int j = 0; j < 4; ++j) {
            float e0 = __builtin_amdgcn_exp2f(acc[0][j] * C2LOG2E);   // s even
            float e1 = __builtin_amdgcn_exp2f(acc[1][j] * C2LOG2E);   // s odd
            __half2 p = __floats2half2_rn(e0, e1);
            ((unsigned int*)&pk)[j] = *(unsigned int*)&p;
        }
        g_ekT4[((size_t)b * (H_ / 4) + h4) * (LK_ / 2) + (s0 >> 1)] = pk;
    }
}

// Fused scores + softmax + PV, one row per block: 1024 x 512 (32 waves/CU).
// Phase 1: exp folded into the score (shift-invariance; |score| <= 2||w||_1
// ~ 18 << 88 so no max-subtraction needed); 8-deep batched uint4 loads.
// Phase 2: single shfl+LDS sum reduce. Phase 3: PV uint2 loads, 16-way
// s-split, 8-deep batches. Masked s never computed (weight exactly 0).
__global__ __launch_bounds__(512, 8) void fused_attn(const int* __restrict__ valid_lens,
                                                     const float* __restrict__ w_v,
                                                     float* __restrict__ out) {
    __shared__ float sc[LK_];
    __shared__ float sred[8];
    __shared__ float rinv_s;
    __shared__ float part[16][H_];
    const int t = threadIdx.x;
    const int lane = t & 63, wid = t >> 6;
    const int b = blockIdx.x >> 7, l = blockIdx.x & 127;
    int valid = valid_lens[b];
    valid = min(max(valid, 0), LK_);

    // ---- Phase 1: scores -> weights (exp folded), masked partial sums ----
    const int s0 = 2 * t;
    float e0 = 0.0f, e1 = 0.0f;
    if (valid == 0) {
        for (int i = t; i < LK_; i += 512) sc[i] = 1.0f;
    } else if (s0 < valid) {
        const float* __restrict__ q0 = g_eq + (size_t)(b * LQ_ + l) * H_;
        const uint4* __restrict__ ek = g_ekT4 + (size_t)b * (H_ / 4) * (LK_ / 2) + t;
        float a0 = 0.0f, a1 = 0.0f;
        #pragma unroll
        for (int hb = 0; hb < 4; ++hb) {             // 4 batches x 8 h4
            uint4 r[8];
            #pragma unroll
            for (int i = 0; i < 8; ++i)
                r[i] = ek[(size_t)(hb * 8 + i) * (LK_ / 2)];
            #pragma unroll
            for (int i = 0; i < 8; ++i) {
                #pragma unroll
                for (int j = 0; j < 4; ++j) {
                    unsigned int uj = ((const unsigned int*)&r[i])[j];
                    float2 ef = __half22float2(*(const __half2*)&uj);
                    const int h = (hb * 8 + i) * 4 + j;
                    const float qh = q0[h], wh = w_v[h];
                    a0 = fmaf(wh, __builtin_amdgcn_rcpf(fmaf(qh, ef.x, 1.0f)), a0);
                    a1 = fmaf(wh, __builtin_amdgcn_rcpf(fmaf(qh, ef.y, 1.0f)), a1);
                }
            }
        }
        e0 = __builtin_amdgcn_exp2f(a0 * (-2.0f * 1.44269504f));
        float e1f = __builtin_amdgcn_exp2f(a1 * (-2.0f * 1.44269504f));
        *(float2*)(sc + s0) = make_float2(e0, e1f);
        e1 = (s0 + 1 < valid) ? e1f : 0.0f;
    }
    // ---- Phase 2: sum reduce over in-register weights ----
    float ps = e0 + e1;
    #pragma unroll
    for (int kk = 32; kk; kk >>= 1) ps += __shfl_xor(ps, kk, 64);
    if (lane == 0) sred[wid] = ps;
    __syncthreads();
    if (t == 0) {
        float s8 = ((sred[0] + sred[1]) + (sred[2] + sred[3]))
                 + ((sred[4] + sred[5]) + (sred[6] + sred[7]));
        rinv_s = (valid == 0) ? (1.0f / 1024.0f) : (1.0f / s8);
    }
    __syncthreads();
    const float rinv = rinv_s;
    const int n = (valid == 0) ? LK_ : valid;

    // ---- Phase 3: PV. uint2 = 4 v per lane; 16-way s-split, 8-deep batches ----
    const int c = t >> 5;                // s-chunk [0,16)
    const int v4 = t & 31;               // 4-v group
    const uint2* vb = (const uint2*)g_vh + (size_t)b * LK_ * (H_ / 4) + v4;
    float ax = 0.0f, ay = 0.0f, az = 0.0f, aw = 0.0f;
    int s = c;
    for (; s + 16 * 7 < n; s += 16 * 8) {
        uint2 r[8];
        #pragma unroll
        for (int i = 0; i < 8; ++i)
            r[i] = vb[(size_t)(s + 16 * i) * (H_ / 4)];
        #pragma unroll
        for (int i = 0; i < 8; ++i) {
            float2 v01 = __half22float2(*(const __half2*)&r[i].x);
            float2 v23 = __half22float2(*(const __half2*)&r[i].y);
            float w = sc[s + 16 * i];
            ax = fmaf(w, v01.x, ax); ay = fmaf(w, v01.y, ay);
            az = fmaf(w, v23.x, az); aw = fmaf(w, v23.y, aw);
        }
    }
    for (; s < n; s += 16) {
        uint2 u = vb[(size_t)s * (H_ / 4)];
        float2 v01 = __half22float2(*(const __half2*)&u.x);
        float2 v23 = __half22float2(*(const __half2*)&u.y);
        float w = sc[s];
        ax = fmaf(w, v01.x, ax); ay = fmaf(w, v01.y, ay);
        az = fmaf(w, v23.x, az); aw = fmaf(w, v23.y, aw);
    }
    *(float4*)(&part[c][4 * v4]) = make_float4(ax, ay, az, aw);
    __syncthreads();
    if (t < H_) {
        float o = 0.0f;
        #pragma unroll
        for (int cc2 = 0; cc2 < 16; ++cc2) o += part[cc2][t];
        out[(b * LQ_ + l) * H_ + t] = o * rinv;
    }
}

extern "C" void kernel_launch(void* const* d_in, const int* in_sizes, int n_in,
                              void* d_out, int out_size, void* d_ws, size_t ws_size,
                              hipStream_t stream) {
    const float* queries    = (const float*)d_in[0];
    const float* keys       = (const float*)d_in[1];
    const float* values     = (const float*)d_in[2];
    const int*   valid_lens = (const int*)d_in[3];
    const float* W_q        = (const float*)d_in[4];
    const float* W_k        = (const float*)d_in[5];
    const float* w_v        = (const float*)d_in[6];
    float* out = (float*)d_out;
    (void)d_ws; (void)ws_size; (void)in_sizes; (void)n_in; (void)out_size;

    proj_conv <<<dim3(800, 2), 256, 0, stream>>>(queries, keys, W_q, W_k, values);
    fused_attn<<<1024, 512, 0, stream>>>(valid_lens, w_v, out);
}